// Round 5
// baseline (1017.126 us; speedup 1.0000x reference)
//
#include <hip/hip_runtime.h>
#include <stdint.h>
#include <stddef.h>

#define NN 10000          // nodes (rows of the reshaped matrix)
#define NE 320000         // edges per support
#define NSUP 2
#define CB 4096           // row width = C_IN * BATCH
#define RPS 10016         // rowptr stride per support
#define NCHUNK 16         // column chunks; 5.12MB chunk (1.28x L2) at dwordx2 gathers
#define CHUNK_B 512       // bytes per row per chunk (256 cols * 2B)
#define PEPAD 400016      // padded edge capacity per support

typedef unsigned int uint32;
typedef unsigned short u16;
typedef __attribute__((ext_vector_type(8))) short bf16x8;
typedef __attribute__((ext_vector_type(8))) u16 u16x8;
typedef __attribute__((ext_vector_type(4))) float f32x4;
typedef __attribute__((ext_vector_type(2))) uint32 u32x2;   // nontemporal-friendly 8B vector

__device__ __forceinline__ float bf2f(u16 u) {
    union { unsigned int i; float f; } v; v.i = ((unsigned int)u) << 16; return v.f;
}
__device__ __forceinline__ u16 f2bf(float f) {
    union { float f; unsigned int i; } v; v.f = f;
    unsigned int u = v.i;
    return (u16)((u + 0x7fffu + ((u >> 16) & 1u)) >> 16);  // RNE, finite inputs
}

// ---------- phase 0: per-row 64x64 transpose (j=c*64+b -> b*64+c) + fp32->bf16 ----------
__global__ __launch_bounds__(256) void k_transpose(const float* __restrict__ x,
                                                   u16* __restrict__ xT) {
    __shared__ float tile[4160];            // 4096 + 64 pad (stride 65 on transposed read)
    const int row = blockIdx.x;
    const int tid = threadIdx.x;
    const f32x4* src = (const f32x4*)(x + (size_t)row * CB);
    #pragma unroll
    for (int q = 0; q < 4; ++q) {
        f32x4 v = src[tid + q * 256];
        int j0 = (tid + q * 256) * 4;
        #pragma unroll
        for (int r = 0; r < 4; ++r) {
            int j = j0 + r;
            tile[j + (j >> 6)] = v[r];
        }
    }
    __syncthreads();
    u16x8 o0, o1;
    #pragma unroll
    for (int jj = 0; jj < 16; ++jj) {
        int j = tid * 16 + jj;              // output index b*64+c
        int b = j >> 6, c = j & 63;
        u16 t = f2bf(tile[c * 65 + b]);     // padded index of c*64+b
        if (jj < 8) o0[jj] = t; else o1[jj - 8] = t;
    }
    u16x8* dst = (u16x8*)(xT + (size_t)row * CB + tid * 16);
    dst[0] = o0; dst[1] = o1;
}

// ---------- CSR build ----------
__global__ __launch_bounds__(256) void k_zero(int* __restrict__ p, int n) {
    int i = blockIdx.x * 256 + threadIdx.x;
    if (i < n) p[i] = 0;
}

__global__ __launch_bounds__(256) void k_hist(const int* __restrict__ rows,
                                              int* __restrict__ counts) {
    int g = blockIdx.x * 256 + threadIdx.x;
    if (g >= NSUP * NE) return;
    int s = g / NE;
    atomicAdd(&counts[s * RPS + rows[g]], 1);
}

// exclusive scan of counts padded up to multiples of 8 (pad edges are zero-valued no-ops)
__global__ __launch_bounds__(1024) void k_scan(const int* __restrict__ counts,
                                               int* __restrict__ rowptr,
                                               int* __restrict__ cursor) {
    const int s = blockIdx.x;
    const int tid = threadIdx.x;
    __shared__ int buf[1024];
    __shared__ int carry_s;
    if (tid == 0) carry_s = 0;
    __syncthreads();
    for (int base = 0; base < NN; base += 1024) {
        int i = base + tid;
        int v = (i < NN) ? ((counts[s * RPS + i] + 7) & ~7) : 0;
        buf[tid] = v;
        __syncthreads();
        for (int off = 1; off < 1024; off <<= 1) {
            int t = (tid >= off) ? buf[tid - off] : 0;
            __syncthreads();
            buf[tid] += t;
            __syncthreads();
        }
        int carry = carry_s;
        int excl = carry + buf[tid] - v;
        if (i < NN) { rowptr[s * RPS + i] = excl; cursor[s * RPS + i] = excl; }
        __syncthreads();
        if (tid == 1023) carry_s = carry + buf[1023];
        __syncthreads();
    }
    if (tid == 0) rowptr[s * RPS + NN] = carry_s;
}

__global__ __launch_bounds__(256) void k_scatter(const int* __restrict__ rows,
                                                 const int* __restrict__ cols,
                                                 const float* __restrict__ vals,
                                                 int* __restrict__ cursor,
                                                 uint2* __restrict__ pedges) {
    int g = blockIdx.x * 256 + threadIdx.x;
    if (g >= NSUP * NE) return;
    int s = g / NE;
    int r = rows[g];
    int pos = atomicAdd(&cursor[s * RPS + r], 1);
    uint2 p;
    p.x = (unsigned int)cols[g];
    p.y = __float_as_uint(vals[g]);
    pedges[(size_t)s * PEPAD + pos] = p;
}

// ---------- Theta -> MFMA B-fragment layout, bf16 ----------
__global__ __launch_bounds__(256) void k_theta(const float* __restrict__ Theta,
                                               u16* __restrict__ thetaFrag) {
    int idx = blockIdx.x * 256 + threadIdx.x;
    if (idx >= 20480) return;
    int j = idx & 7;
    int lane = (idx >> 3) & 63;
    int ct = (idx >> 9) & 3;
    int ks = idx >> 11;
    int kp = ks * 32 + ((lane >> 4) << 3) + j;
    int m = kp >> 6, c = kp & 63;
    int co = ct * 16 + (lane & 15);
    thetaFrag[idx] = f2bf(Theta[(c * 5 + m) * 64 + co]);
}

// ---------- SpMM inner loop: 8-edge blocks, dwordx2 gathers (8B/lane) ----------
// Edge loads are wave-uniform-address; the compiler scalarizes them to s_load
// with (col,val) in SGPRs (Round-0 evidence: VGPR_Count=16). Gather base
// src + (col<<13) is then scalar math + saddr-form global_load_dwordx2 with a
// single loop-invariant VGPR offset. NAMED double buffers, no runtime indexing.
#define GATHER8(G, M)                                                           \
    _Pragma("unroll")                                                           \
    for (int j = 0; j < 8; ++j)                                                 \
        (G)[j] = *(const u32x2*)(srcb + (((M)[j].x << 13) + cb));

#define PREFETCH8(M, blk)                                                       \
    {                                                                           \
        const uint2* pn_ = pe + (size_t)(blk) * 8;                              \
        _Pragma("unroll")                                                       \
        for (int j = 0; j < 8; ++j) (M)[j] = pn_[j];                            \
    }

#define FMA8(G, M)                                                              \
    _Pragma("unroll")                                                           \
    for (int j = 0; j < 8; ++j) {                                               \
        float v_ = __uint_as_float((M)[j].y);                                   \
        a0 = fmaf(v_, __uint_as_float((G)[j].x << 16), a0);                     \
        a1 = fmaf(v_, __uint_as_float((G)[j].x & 0xffff0000u), a1);             \
        a2 = fmaf(v_, __uint_as_float((G)[j].y << 16), a2);                     \
        a3 = fmaf(v_, __uint_as_float((G)[j].y & 0xffff0000u), a3);             \
    }

__device__ __forceinline__ void spmm_core(const char* __restrict__ srcb,
                                          const uint2* __restrict__ pe,
                                          int nblk, uint32 cb,
                                          float& a0, float& a1,
                                          float& a2, float& a3) {
    uint2 ma[8], mb[8];
    u32x2 ga[8], gb[8];
    PREFETCH8(ma, 0)
    int b = 0;
    for (; b + 2 <= nblk; b += 2) {
        GATHER8(ga, ma)
        PREFETCH8(mb, b + 1)
        FMA8(ga, ma)
        GATHER8(gb, mb)
        PREFETCH8(ma, b + 2)
        FMA8(gb, mb)
    }
    if (b < nblk) {
        GATHER8(ga, ma)
        FMA8(ga, ma)
    }
}

// ---------- chunked SpMM, hop 1 (both supports fused, src = m0, beta = 0) ----------
__global__ __launch_bounds__(256) void k_spmm1(const u16* __restrict__ src,
                                               u16* __restrict__ dst0,
                                               u16* __restrict__ dst1,
                                               const int* __restrict__ rowptr,
                                               const uint2* __restrict__ pedges) {
    const int bx = blockIdx.x;
    const int chunk = bx / (2 * (NN / 4));
    const int r2 = bx - chunk * (2 * (NN / 4));
    const int s = r2 & 1;
    const int quad = r2 >> 1;
    const int wave = threadIdx.x >> 6, lane = threadIdx.x & 63;
    const int row = quad * 4 + wave;
    const uint32 cb = (uint32)chunk * CHUNK_B + (uint32)lane * 8;  // byte offset in row
    const int* rp = rowptr + s * RPS;
    const int e0 = __builtin_amdgcn_readfirstlane(rp[row]);
    const int e1 = __builtin_amdgcn_readfirstlane(rp[row + 1]);
    const uint2* pe = pedges + (size_t)s * PEPAD + e0;
    float a0 = 0.f, a1 = 0.f, a2 = 0.f, a3 = 0.f;
    spmm_core((const char*)src, pe, (e1 - e0) >> 3, cb, a0, a1, a2, a3);
    u16* dst = s ? dst1 : dst0;
    u32x2 o;
    o.x = (uint32)f2bf(a0) | ((uint32)f2bf(a1) << 16);
    o.y = (uint32)f2bf(a2) | ((uint32)f2bf(a3) << 16);
    __builtin_nontemporal_store(o, (u32x2*)((char*)dst + (size_t)row * (CB * 2) + cb));
}

// ---------- merged chunked SpMM, hop 2 (both supports): dst = 2*A*src - m0 ----------
// Block order is chunk-major with support inner, so at any instant roughly one
// 5.12MB source chunk is hot per XCD L2 (supports processed back-to-back per
// chunk index, same as an intra-kernel chunk transition).
__global__ __launch_bounds__(256) void k_spmm2(const u16* __restrict__ src0,
                                               const u16* __restrict__ src1,
                                               const u16* __restrict__ aux,
                                               u16* __restrict__ dst0,
                                               u16* __restrict__ dst1,
                                               const int* __restrict__ rowptr,
                                               const uint2* __restrict__ pedges) {
    const int bx = blockIdx.x;
    const int chunk = bx / (2 * (NN / 4));
    const int r2 = bx - chunk * (2 * (NN / 4));
    const int s = r2 / (NN / 4);                 // support inner, contiguous per chunk
    const int quad = r2 - s * (NN / 4);
    const int wave = threadIdx.x >> 6, lane = threadIdx.x & 63;
    const int row = quad * 4 + wave;
    const uint32 cb = (uint32)chunk * CHUNK_B + (uint32)lane * 8;
    const int* rp = rowptr + s * RPS;
    const int e0 = __builtin_amdgcn_readfirstlane(rp[row]);
    const int e1 = __builtin_amdgcn_readfirstlane(rp[row + 1]);
    const uint2* pe = pedges + (size_t)s * PEPAD + e0;
    const char* srcb = (const char*)(s ? src1 : src0);
    float a0 = 0.f, a1 = 0.f, a2 = 0.f, a3 = 0.f;
    spmm_core(srcb, pe, (e1 - e0) >> 3, cb, a0, a1, a2, a3);
    const size_t rowoff = (size_t)row * (CB * 2) + cb;
    u32x2 av = __builtin_nontemporal_load((const u32x2*)((const char*)aux + rowoff));
    u32x2 o;
    {
        float c0 = 2.f * a0 - __uint_as_float(av.x << 16);
        float c1 = 2.f * a1 - __uint_as_float(av.x & 0xffff0000u);
        float c2 = 2.f * a2 - __uint_as_float(av.y << 16);
        float c3 = 2.f * a3 - __uint_as_float(av.y & 0xffff0000u);
        o.x = (uint32)f2bf(c0) | ((uint32)f2bf(c1) << 16);
        o.y = (uint32)f2bf(c2) | ((uint32)f2bf(c3) << 16);
    }
    u16* dst = s ? dst1 : dst0;
    __builtin_nontemporal_store(o, (u32x2*)((char*)dst + rowoff));
}

// ---------- phase 2: per-node (64 x 320) @ (320 x 64) via MFMA, bias fused ----------
__global__ __launch_bounds__(256) void k_gemm(const u16* __restrict__ mats,
                                              const u16* __restrict__ thetaFrag,
                                              const float* __restrict__ bias,
                                              float* __restrict__ out) {
    __shared__ u16 th[20480];   // 40KB
    const int tid = threadIdx.x;
    #pragma unroll
    for (int q = 0; q < 10; ++q) {
        int idx = tid * 8 + q * 2048;
        *(u16x8*)&th[idx] = *(const u16x8*)&thetaFrag[idx];
    }
    __syncthreads();
    const int wave = tid >> 6, lane = tid & 63;
    const int node = blockIdx.x * 4 + wave;
    const int l15 = lane & 15, lhi = lane >> 4;

    f32x4 acc[4][4];
    #pragma unroll
    for (int ct = 0; ct < 4; ++ct) {
        float bv = bias[ct * 16 + l15];
        #pragma unroll
        for (int bt = 0; bt < 4; ++bt) {
            acc[bt][ct][0] = bv; acc[bt][ct][1] = bv; acc[bt][ct][2] = bv; acc[bt][ct][3] = bv;
        }
    }
    #pragma unroll
    for (int ks = 0; ks < 10; ++ks) {
        const int m = ks >> 1;
        const int c0 = ((ks & 1) << 5) + (lhi << 3);
        const u16* mbase = mats + (size_t)m * ((size_t)NN * CB) + (size_t)node * CB;
        bf16x8 af[4];
        #pragma unroll
        for (int bt = 0; bt < 4; ++bt)
            af[bt] = *(const bf16x8*)(mbase + (bt * 16 + l15) * 64 + c0);
        #pragma unroll
        for (int ct = 0; ct < 4; ++ct) {
            bf16x8 bf = *(const bf16x8*)&th[((ks * 4 + ct) * 64 + lane) * 8];
            #pragma unroll
            for (int bt = 0; bt < 4; ++bt)
                acc[bt][ct] = __builtin_amdgcn_mfma_f32_16x16x32_bf16(af[bt], bf, acc[bt][ct], 0, 0, 0);
        }
    }
    #pragma unroll
    for (int bt = 0; bt < 4; ++bt)
        #pragma unroll
        for (int ct = 0; ct < 4; ++ct)
            #pragma unroll
            for (int r = 0; r < 4; ++r) {
                int b = bt * 16 + lhi * 4 + r;
                int co = ct * 16 + l15;
                out[(size_t)b * (NN * 64) + (size_t)node * 64 + co] = acc[bt][ct][r];
            }
}

extern "C" void kernel_launch(void* const* d_in, const int* in_sizes, int n_in,
                              void* d_out, int out_size, void* d_ws, size_t ws_size,
                              hipStream_t stream) {
    const float* x         = (const float*)d_in[0];
    const float* edge_vals = (const float*)d_in[1];
    const float* Theta     = (const float*)d_in[2];
    const float* bias      = (const float*)d_in[3];
    const int*   edge_rows = (const int*)d_in[4];
    const int*   edge_cols = (const int*)d_in[5];
    float* out = (float*)d_out;

    uint8_t* ws = (uint8_t*)d_ws;
    const size_t MAT_E = (size_t)NN * CB;      // 40,960,000 elements
    const size_t MAT_B = MAT_E * 2;            // bytes per bf16 matrix

    u16* mats      = (u16*)ws;                          // 5 contiguous matrices
    u16* thetaFrag = (u16*)(ws + 5 * MAT_B);
    uint8_t* p = ws + 5 * MAT_B + 40960;
    int* counts = (int*)p;  p += (size_t)NSUP * RPS * 4;
    int* rowptr = (int*)p;  p += (size_t)NSUP * RPS * 4;
    int* cursor = (int*)p;  p += (size_t)NSUP * RPS * 4;
    p = (uint8_t*)(((uintptr_t)p + 255) & ~(uintptr_t)255);
    uint2* pedges = (uint2*)p;                          // 2 * PEPAD * 8B (zero-padded CSR)

    u16* m0 = mats;
    u16* m1 = mats + MAT_E;
    u16* m2 = mats + 2 * MAT_E;
    u16* m3 = mats + 3 * MAT_E;
    u16* m4 = mats + 4 * MAT_E;

    // phase 0 + CSR build + Theta pack
    k_transpose<<<NN, 256, 0, stream>>>(x, m0);
    k_zero<<<(NSUP * RPS + 255) / 256, 256, 0, stream>>>(counts, NSUP * RPS);
    k_zero<<<(NSUP * PEPAD * 2 + 255) / 256, 256, 0, stream>>>((int*)pedges, NSUP * PEPAD * 2);
    k_hist<<<(NSUP * NE) / 256, 256, 0, stream>>>(edge_rows, counts);
    k_scan<<<NSUP, 1024, 0, stream>>>(counts, rowptr, cursor);
    k_scatter<<<(NSUP * NE) / 256, 256, 0, stream>>>(edge_rows, edge_cols, edge_vals,
                                                     cursor, pedges);
    k_theta<<<80, 256, 0, stream>>>(Theta, thetaFrag);

    // diffusion chain, column-chunked; dwordx2 gathers halve transactions/edge
    k_spmm1<<<NCHUNK * (NN / 4) * 2, 256, 0, stream>>>(m0, m1, m3, rowptr, pedges);
    k_spmm2<<<NCHUNK * (NN / 4) * 2, 256, 0, stream>>>(m1, m3, m0, m2, m4,
                                                       rowptr, pedges);

    // output projection
    k_gemm<<<NN / 4, 256, 0, stream>>>(mats, thetaFrag, bias, out);
}

// Round 6
// 962.692 us; speedup vs baseline: 1.0565x; 1.0565x over previous
//
#include <hip/hip_runtime.h>
#include <stdint.h>
#include <stddef.h>

#define NN 10000          // nodes (rows of the reshaped matrix)
#define NE 320000         // edges per support
#define NSUP 2
#define CB 4096           // row width = C_IN * BATCH
#define RPS 10016         // rowptr stride per support
#define NCHUNK 32         // column chunks for L2-resident SpMM (2.56 MB per chunk)
#define CHUNK_B 256       // bytes per row per chunk (128 cols * 2B)
#define PEPAD 400016      // padded edge capacity per support
#define NXCD 8

typedef unsigned int uint32;
typedef unsigned short u16;
typedef __attribute__((ext_vector_type(8))) short bf16x8;
typedef __attribute__((ext_vector_type(8))) u16 u16x8;
typedef __attribute__((ext_vector_type(4))) float f32x4;

__device__ __forceinline__ float bf2f(u16 u) {
    union { unsigned int i; float f; } v; v.i = ((unsigned int)u) << 16; return v.f;
}
__device__ __forceinline__ u16 f2bf(float f) {
    union { float f; unsigned int i; } v; v.f = f;
    unsigned int u = v.i;
    return (u16)((u + 0x7fffu + ((u >> 16) & 1u)) >> 16);  // RNE, finite inputs
}

// ---------- phase 0: per-row 64x64 transpose (j=c*64+b -> b*64+c) + fp32->bf16 ----------
__global__ __launch_bounds__(256) void k_transpose(const float* __restrict__ x,
                                                   u16* __restrict__ xT) {
    __shared__ float tile[4160];            // 4096 + 64 pad (stride 65 on transposed read)
    const int row = blockIdx.x;
    const int tid = threadIdx.x;
    const f32x4* src = (const f32x4*)(x + (size_t)row * CB);
    #pragma unroll
    for (int q = 0; q < 4; ++q) {
        f32x4 v = src[tid + q * 256];
        int j0 = (tid + q * 256) * 4;
        #pragma unroll
        for (int r = 0; r < 4; ++r) {
            int j = j0 + r;
            tile[j + (j >> 6)] = v[r];
        }
    }
    __syncthreads();
    u16x8 o0, o1;
    #pragma unroll
    for (int jj = 0; jj < 16; ++jj) {
        int j = tid * 16 + jj;              // output index b*64+c
        int b = j >> 6, c = j & 63;
        u16 t = f2bf(tile[c * 65 + b]);     // padded index of c*64+b
        if (jj < 8) o0[jj] = t; else o1[jj - 8] = t;
    }
    u16x8* dst = (u16x8*)(xT + (size_t)row * CB + tid * 16);
    dst[0] = o0; dst[1] = o1;
}

// ---------- CSR build ----------
__global__ __launch_bounds__(256) void k_zero(int* __restrict__ p, int n) {
    int i = blockIdx.x * 256 + threadIdx.x;
    if (i < n) p[i] = 0;
}

__global__ __launch_bounds__(256) void k_hist(const int* __restrict__ rows,
                                              int* __restrict__ counts) {
    int g = blockIdx.x * 256 + threadIdx.x;
    if (g >= NSUP * NE) return;
    int s = g / NE;
    atomicAdd(&counts[s * RPS + rows[g]], 1);
}

// exclusive scan of counts padded up to multiples of 8 (pad edges are zero-valued no-ops)
__global__ __launch_bounds__(1024) void k_scan(const int* __restrict__ counts,
                                               int* __restrict__ rowptr,
                                               int* __restrict__ cursor) {
    const int s = blockIdx.x;
    const int tid = threadIdx.x;
    __shared__ int buf[1024];
    __shared__ int carry_s;
    if (tid == 0) carry_s = 0;
    __syncthreads();
    for (int base = 0; base < NN; base += 1024) {
        int i = base + tid;
        int v = (i < NN) ? ((counts[s * RPS + i] + 7) & ~7) : 0;
        buf[tid] = v;
        __syncthreads();
        for (int off = 1; off < 1024; off <<= 1) {
            int t = (tid >= off) ? buf[tid - off] : 0;
            __syncthreads();
            buf[tid] += t;
            __syncthreads();
        }
        int carry = carry_s;
        int excl = carry + buf[tid] - v;
        if (i < NN) { rowptr[s * RPS + i] = excl; cursor[s * RPS + i] = excl; }
        __syncthreads();
        if (tid == 1023) carry_s = carry + buf[1023];
        __syncthreads();
    }
    if (tid == 0) rowptr[s * RPS + NN] = carry_s;
}

__global__ __launch_bounds__(256) void k_scatter(const int* __restrict__ rows,
                                                 const int* __restrict__ cols,
                                                 const float* __restrict__ vals,
                                                 int* __restrict__ cursor,
                                                 uint2* __restrict__ pedges) {
    int g = blockIdx.x * 256 + threadIdx.x;
    if (g >= NSUP * NE) return;
    int s = g / NE;
    int r = rows[g];
    int pos = atomicAdd(&cursor[s * RPS + r], 1);
    uint2 p;
    p.x = (unsigned int)cols[g];
    p.y = __float_as_uint(vals[g]);
    pedges[(size_t)s * PEPAD + pos] = p;
}

// ---------- Theta -> MFMA B-fragment layout, bf16 ----------
__global__ __launch_bounds__(256) void k_theta(const float* __restrict__ Theta,
                                               u16* __restrict__ thetaFrag) {
    int idx = blockIdx.x * 256 + threadIdx.x;
    if (idx >= 20480) return;
    int j = idx & 7;
    int lane = (idx >> 3) & 63;
    int ct = (idx >> 9) & 3;
    int ks = idx >> 11;
    int kp = ks * 32 + ((lane >> 4) << 3) + j;
    int m = kp >> 6, c = kp & 63;
    int co = ct * 16 + (lane & 15);
    thetaFrag[idx] = f2bf(Theta[(c * 5 + m) * 64 + co]);
}

// ---------- SpMM inner loop: 3-way rotated 8-edge buffers, 24 gathers in flight ----------
// KEY ordering fix vs the 2-buffer version: each FMA's vmcnt wait always has the
// other two buffers' 16 gathers outstanding, and the freed buffer is re-issued
// immediately after consumption -> steady-state ~24 loads in flight per wave
// (was ~8 draining to 0 every block -> exposed L2 latency).
#define PRE8(E, blk)                                                            \
    {                                                                           \
        const uint2* pn_ = pe + (size_t)(blk) * 8;                              \
        _Pragma("unroll")                                                       \
        for (int j = 0; j < 8; ++j) (E)[j] = pn_[j];                            \
    }

#define GAT8(G, E)                                                              \
    _Pragma("unroll")                                                           \
    for (int j = 0; j < 8; ++j)                                                 \
        (G)[j] = *(const uint32*)(srcb + (((E)[j].x << 13) + cb));

#define FMA8(G, E)                                                              \
    _Pragma("unroll")                                                           \
    for (int j = 0; j < 8; ++j) {                                               \
        float v_ = __uint_as_float((E)[j].y);                                   \
        a0 = fmaf(v_, __uint_as_float((G)[j] << 16), a0);                       \
        a1 = fmaf(v_, __uint_as_float((G)[j] & 0xffff0000u), a1);               \
    }

__device__ __forceinline__ void spmm_core(const char* __restrict__ srcb,
                                          const uint2* __restrict__ pe,
                                          int nblk, uint32 cb,
                                          float& a0, float& a1) {
    uint2 e0[8], e1[8], e2[8];
    uint32 g0[8], g1[8], g2[8];
    if (nblk >= 3) {
        PRE8(e0, 0) GAT8(g0, e0)
        PRE8(e1, 1) GAT8(g1, e1)
        PRE8(e2, 2) GAT8(g2, e2)
        int b = 0;
        for (; b + 6 <= nblk; b += 3) {
            FMA8(g0, e0) PRE8(e0, b + 3) GAT8(g0, e0)
            FMA8(g1, e1) PRE8(e1, b + 4) GAT8(g1, e1)
            FMA8(g2, e2) PRE8(e2, b + 5) GAT8(g2, e2)
        }
        const int r = nblk - b;             // 3, 4, or 5
        FMA8(g0, e0)
        if (r >= 4) { PRE8(e0, b + 3) GAT8(g0, e0) }
        FMA8(g1, e1)
        if (r == 5) { PRE8(e1, b + 4) GAT8(g1, e1) }
        FMA8(g2, e2)
        if (r >= 4) FMA8(g0, e0)
        if (r == 5) FMA8(g1, e1)
    } else {
        for (int t = 0; t < nblk; ++t) {
            PRE8(e0, t) GAT8(g0, e0) FMA8(g0, e0)
        }
    }
}

// ---------- chunked SpMM, hop 1 (both supports fused, src = m0, beta = 0) ----------
// bx&7 XCD swizzle (round-1: -112MB FETCH) + chunk-major ordering.
__global__ __launch_bounds__(256) void k_spmm1(const u16* __restrict__ src,
                                               u16* __restrict__ dst0,
                                               u16* __restrict__ dst1,
                                               const int* __restrict__ rowptr,
                                               const uint2* __restrict__ pedges) {
    const int bx = blockIdx.x;
    const int xcd = bx & (NXCD - 1);
    const int l = bx >> 3;                       // 0 .. 4*5000-1 per XCD
    const int cwx = l / (2 * (NN / 4));          // chunk-within-xcd, 0..3
    const int r2 = l - cwx * (2 * (NN / 4));
    const int chunk = xcd * (NCHUNK / NXCD) + cwx;
    const int s = r2 & 1;
    const int quad = r2 >> 1;
    const int wave = threadIdx.x >> 6, lane = threadIdx.x & 63;
    const int row = quad * 4 + wave;
    const uint32 cb = (uint32)chunk * CHUNK_B + (uint32)lane * 4;  // byte offset in row
    const int* rp = rowptr + s * RPS;
    const int e0 = __builtin_amdgcn_readfirstlane(rp[row]);
    const int e1 = __builtin_amdgcn_readfirstlane(rp[row + 1]);
    const uint2* pe = pedges + (size_t)s * PEPAD + e0;
    float a0 = 0.f, a1 = 0.f;
    spmm_core((const char*)src, pe, (e1 - e0) >> 3, cb, a0, a1);
    u16* dst = s ? dst1 : dst0;
    uint32 o = (uint32)f2bf(a0) | ((uint32)f2bf(a1) << 16);
    __builtin_nontemporal_store(o, (uint32*)((char*)dst + (size_t)row * (CB * 2) + cb));
}

// ---------- merged chunked SpMM, hop 2 (both supports): dst = 2*A*src - m0 ----------
// support-inner ordering within each chunk slot -> ~one 2.56MB src slice hot at a time
__global__ __launch_bounds__(256) void k_spmm2(const u16* __restrict__ src0,
                                               const u16* __restrict__ src1,
                                               const u16* __restrict__ aux,
                                               u16* __restrict__ dst0,
                                               u16* __restrict__ dst1,
                                               const int* __restrict__ rowptr,
                                               const uint2* __restrict__ pedges) {
    const int bx = blockIdx.x;
    const int xcd = bx & (NXCD - 1);
    const int l = bx >> 3;
    const int cwx = l / (2 * (NN / 4));
    const int r2 = l - cwx * (2 * (NN / 4));
    const int chunk = xcd * (NCHUNK / NXCD) + cwx;
    const int s = r2 / (NN / 4);
    const int quad = r2 - s * (NN / 4);
    const int wave = threadIdx.x >> 6, lane = threadIdx.x & 63;
    const int row = quad * 4 + wave;
    const uint32 cb = (uint32)chunk * CHUNK_B + (uint32)lane * 4;
    const int* rp = rowptr + s * RPS;
    const int e0 = __builtin_amdgcn_readfirstlane(rp[row]);
    const int e1 = __builtin_amdgcn_readfirstlane(rp[row + 1]);
    const uint2* pe = pedges + (size_t)s * PEPAD + e0;
    const char* srcb = (const char*)(s ? src1 : src0);
    float a0 = 0.f, a1 = 0.f;
    spmm_core(srcb, pe, (e1 - e0) >> 3, cb, a0, a1);
    const size_t rowoff = (size_t)row * (CB * 2) + cb;
    uint32 av = __builtin_nontemporal_load((const uint32*)((const char*)aux + rowoff));
    float c0 = 2.f * a0 - __uint_as_float(av << 16);
    float c1 = 2.f * a1 - __uint_as_float(av & 0xffff0000u);
    uint32 o = (uint32)f2bf(c0) | ((uint32)f2bf(c1) << 16);
    u16* dst = s ? dst1 : dst0;
    __builtin_nontemporal_store(o, (uint32*)((char*)dst + rowoff));
}

// ---------- phase 2: per-node (64 x 320) @ (320 x 64) via MFMA, bias fused ----------
__global__ __launch_bounds__(256) void k_gemm(const u16* __restrict__ mats,
                                              const u16* __restrict__ thetaFrag,
                                              const float* __restrict__ bias,
                                              float* __restrict__ out) {
    __shared__ u16 th[20480];   // 40KB
    const int tid = threadIdx.x;
    #pragma unroll
    for (int q = 0; q < 10; ++q) {
        int idx = tid * 8 + q * 2048;
        *(u16x8*)&th[idx] = *(const u16x8*)&thetaFrag[idx];
    }
    __syncthreads();
    const int wave = tid >> 6, lane = tid & 63;
    const int node = blockIdx.x * 4 + wave;
    const int l15 = lane & 15, lhi = lane >> 4;

    f32x4 acc[4][4];
    #pragma unroll
    for (int ct = 0; ct < 4; ++ct) {
        float bv = bias[ct * 16 + l15];
        #pragma unroll
        for (int bt = 0; bt < 4; ++bt) {
            acc[bt][ct][0] = bv; acc[bt][ct][1] = bv; acc[bt][ct][2] = bv; acc[bt][ct][3] = bv;
        }
    }
    #pragma unroll
    for (int ks = 0; ks < 10; ++ks) {
        const int m = ks >> 1;
        const int c0 = ((ks & 1) << 5) + (lhi << 3);
        const u16* mbase = mats + (size_t)m * ((size_t)NN * CB) + (size_t)node * CB;
        bf16x8 af[4];
        #pragma unroll
        for (int bt = 0; bt < 4; ++bt)
            af[bt] = *(const bf16x8*)(mbase + (bt * 16 + l15) * 64 + c0);
        #pragma unroll
        for (int ct = 0; ct < 4; ++ct) {
            bf16x8 bf = *(const bf16x8*)&th[((ks * 4 + ct) * 64 + lane) * 8];
            #pragma unroll
            for (int bt = 0; bt < 4; ++bt)
                acc[bt][ct] = __builtin_amdgcn_mfma_f32_16x16x32_bf16(af[bt], bf, acc[bt][ct], 0, 0, 0);
        }
    }
    #pragma unroll
    for (int bt = 0; bt < 4; ++bt)
        #pragma unroll
        for (int ct = 0; ct < 4; ++ct)
            #pragma unroll
            for (int r = 0; r < 4; ++r) {
                int b = bt * 16 + lhi * 4 + r;
                int co = ct * 16 + l15;
                out[(size_t)b * (NN * 64) + (size_t)node * 64 + co] = acc[bt][ct][r];
            }
}

extern "C" void kernel_launch(void* const* d_in, const int* in_sizes, int n_in,
                              void* d_out, int out_size, void* d_ws, size_t ws_size,
                              hipStream_t stream) {
    const float* x         = (const float*)d_in[0];
    const float* edge_vals = (const float*)d_in[1];
    const float* Theta     = (const float*)d_in[2];
    const float* bias      = (const float*)d_in[3];
    const int*   edge_rows = (const int*)d_in[4];
    const int*   edge_cols = (const int*)d_in[5];
    float* out = (float*)d_out;

    uint8_t* ws = (uint8_t*)d_ws;
    const size_t MAT_E = (size_t)NN * CB;      // 40,960,000 elements
    const size_t MAT_B = MAT_E * 2;            // bytes per bf16 matrix

    u16* mats      = (u16*)ws;                          // 5 contiguous matrices
    u16* thetaFrag = (u16*)(ws + 5 * MAT_B);
    uint8_t* p = ws + 5 * MAT_B + 40960;
    int* counts = (int*)p;  p += (size_t)NSUP * RPS * 4;
    int* rowptr = (int*)p;  p += (size_t)NSUP * RPS * 4;
    int* cursor = (int*)p;  p += (size_t)NSUP * RPS * 4;
    p = (uint8_t*)(((uintptr_t)p + 255) & ~(uintptr_t)255);
    uint2* pedges = (uint2*)p;                          // 2 * PEPAD * 8B (zero-padded CSR)

    u16* m0 = mats;
    u16* m1 = mats + MAT_E;
    u16* m2 = mats + 2 * MAT_E;
    u16* m3 = mats + 3 * MAT_E;
    u16* m4 = mats + 4 * MAT_E;

    // phase 0 + CSR build + Theta pack
    k_transpose<<<NN, 256, 0, stream>>>(x, m0);
    k_zero<<<(NSUP * RPS + 255) / 256, 256, 0, stream>>>(counts, NSUP * RPS);
    k_zero<<<(NSUP * PEPAD * 2 + 255) / 256, 256, 0, stream>>>((int*)pedges, NSUP * PEPAD * 2);
    k_hist<<<(NSUP * NE) / 256, 256, 0, stream>>>(edge_rows, counts);
    k_scan<<<NSUP, 1024, 0, stream>>>(counts, rowptr, cursor);
    k_scatter<<<(NSUP * NE) / 256, 256, 0, stream>>>(edge_rows, edge_cols, edge_vals,
                                                     cursor, pedges);
    k_theta<<<80, 256, 0, stream>>>(Theta, thetaFrag);

    // diffusion chain, column-chunked for L2 residency; 3-deep pipelined gathers
    k_spmm1<<<NCHUNK * (NN / 4) * 2, 256, 0, stream>>>(m0, m1, m3, rowptr, pedges);
    k_spmm2<<<NCHUNK * (NN / 4) * 2, 256, 0, stream>>>(m1, m3, m0, m2, m4,
                                                       rowptr, pedges);

    // output projection
    k_gemm<<<NN / 4, 256, 0, stream>>>(mats, thetaFrag, bias, out);
}

// Round 7
// 902.973 us; speedup vs baseline: 1.1264x; 1.0661x over previous
//
#include <hip/hip_runtime.h>
#include <stdint.h>
#include <stddef.h>

#define NN 10000          // nodes (rows of the reshaped matrix)
#define NE 320000         // edges per support
#define NSUP 2
#define CB 4096           // row width = C_IN * BATCH
#define RPS 10016         // rowptr stride per support
#define NCHUNK 32         // column chunks for L2-resident SpMM (2.56 MB per chunk)
#define CHUNK_B 256       // bytes per row per chunk (128 cols * 2B)
#define PEPAD 400016      // padded edge capacity per support
#define NXCD 8

typedef unsigned int uint32;
typedef unsigned short u16;
typedef __attribute__((ext_vector_type(8))) short bf16x8;
typedef __attribute__((ext_vector_type(8))) u16 u16x8;
typedef __attribute__((ext_vector_type(4))) float f32x4;

__device__ __forceinline__ float bf2f(u16 u) {
    union { unsigned int i; float f; } v; v.i = ((unsigned int)u) << 16; return v.f;
}
__device__ __forceinline__ u16 f2bf(float f) {
    union { float f; unsigned int i; } v; v.f = f;
    unsigned int u = v.i;
    return (u16)((u + 0x7fffu + ((u >> 16) & 1u)) >> 16);  // RNE, finite inputs
}

// ---------- phase 0: per-row 64x64 transpose (j=c*64+b -> b*64+c) + fp32->bf16 ----------
__global__ __launch_bounds__(256) void k_transpose(const float* __restrict__ x,
                                                   u16* __restrict__ xT) {
    __shared__ float tile[4160];            // 4096 + 64 pad (stride 65 on transposed read)
    const int row = blockIdx.x;
    const int tid = threadIdx.x;
    const f32x4* src = (const f32x4*)(x + (size_t)row * CB);
    #pragma unroll
    for (int q = 0; q < 4; ++q) {
        f32x4 v = src[tid + q * 256];
        int j0 = (tid + q * 256) * 4;
        #pragma unroll
        for (int r = 0; r < 4; ++r) {
            int j = j0 + r;
            tile[j + (j >> 6)] = v[r];
        }
    }
    __syncthreads();
    u16x8 o0, o1;
    #pragma unroll
    for (int jj = 0; jj < 16; ++jj) {
        int j = tid * 16 + jj;              // output index b*64+c
        int b = j >> 6, c = j & 63;
        u16 t = f2bf(tile[c * 65 + b]);     // padded index of c*64+b
        if (jj < 8) o0[jj] = t; else o1[jj - 8] = t;
    }
    u16x8* dst = (u16x8*)(xT + (size_t)row * CB + tid * 16);
    dst[0] = o0; dst[1] = o1;
}

// ---------- CSR build ----------
__global__ __launch_bounds__(256) void k_zero(int* __restrict__ p, int n) {
    int i = blockIdx.x * 256 + threadIdx.x;
    if (i < n) p[i] = 0;
}

__global__ __launch_bounds__(256) void k_hist(const int* __restrict__ rows,
                                              int* __restrict__ counts) {
    int g = blockIdx.x * 256 + threadIdx.x;
    if (g >= NSUP * NE) return;
    int s = g / NE;
    atomicAdd(&counts[s * RPS + rows[g]], 1);
}

// exclusive scan of counts padded up to multiples of 8 (pad edges are zero-valued no-ops)
__global__ __launch_bounds__(1024) void k_scan(const int* __restrict__ counts,
                                               int* __restrict__ rowptr,
                                               int* __restrict__ cursor) {
    const int s = blockIdx.x;
    const int tid = threadIdx.x;
    __shared__ int buf[1024];
    __shared__ int carry_s;
    if (tid == 0) carry_s = 0;
    __syncthreads();
    for (int base = 0; base < NN; base += 1024) {
        int i = base + tid;
        int v = (i < NN) ? ((counts[s * RPS + i] + 7) & ~7) : 0;
        buf[tid] = v;
        __syncthreads();
        for (int off = 1; off < 1024; off <<= 1) {
            int t = (tid >= off) ? buf[tid - off] : 0;
            __syncthreads();
            buf[tid] += t;
            __syncthreads();
        }
        int carry = carry_s;
        int excl = carry + buf[tid] - v;
        if (i < NN) { rowptr[s * RPS + i] = excl; cursor[s * RPS + i] = excl; }
        __syncthreads();
        if (tid == 1023) carry_s = carry + buf[1023];
        __syncthreads();
    }
    if (tid == 0) rowptr[s * RPS + NN] = carry_s;
}

__global__ __launch_bounds__(256) void k_scatter(const int* __restrict__ rows,
                                                 const int* __restrict__ cols,
                                                 const float* __restrict__ vals,
                                                 int* __restrict__ cursor,
                                                 uint2* __restrict__ pedges) {
    int g = blockIdx.x * 256 + threadIdx.x;
    if (g >= NSUP * NE) return;
    int s = g / NE;
    int r = rows[g];
    int pos = atomicAdd(&cursor[s * RPS + r], 1);
    uint2 p;
    p.x = (unsigned int)cols[g];
    p.y = __float_as_uint(vals[g]);
    pedges[(size_t)s * PEPAD + pos] = p;
}

// ---------- Theta -> MFMA B-fragment layout, bf16 ----------
__global__ __launch_bounds__(256) void k_theta(const float* __restrict__ Theta,
                                               u16* __restrict__ thetaFrag) {
    int idx = blockIdx.x * 256 + threadIdx.x;
    if (idx >= 20480) return;
    int j = idx & 7;
    int lane = (idx >> 3) & 63;
    int ct = (idx >> 9) & 3;
    int ks = idx >> 11;
    int kp = ks * 32 + ((lane >> 4) << 3) + j;
    int m = kp >> 6, c = kp & 63;
    int co = ct * 16 + (lane & 15);
    thetaFrag[idx] = f2bf(Theta[(c * 5 + m) * 64 + co]);
}

// ---------- SpMM inner loop: 8-edge blocks, NAMED double buffers (R1-verified best) ----------
#define GATHER8(M)                                                              \
    _Pragma("unroll")                                                           \
    for (int j = 0; j < 8; ++j)                                                 \
        u[j] = *(const uint32*)(srcb + (((M)[j].x << 13) + cb));

#define PREFETCH8(M, blk)                                                       \
    {                                                                           \
        const uint2* pn_ = pe + (size_t)(blk) * 8;                              \
        _Pragma("unroll")                                                       \
        for (int j = 0; j < 8; ++j) (M)[j] = pn_[j];                            \
    }

#define FMA8(M)                                                                 \
    _Pragma("unroll")                                                           \
    for (int j = 0; j < 8; ++j) {                                               \
        float v_ = __uint_as_float((M)[j].y);                                   \
        a0 = fmaf(v_, __uint_as_float(u[j] << 16), a0);                         \
        a1 = fmaf(v_, __uint_as_float(u[j] & 0xffff0000u), a1);                 \
    }

__device__ __forceinline__ void spmm_core(const char* __restrict__ srcb,
                                          const uint2* __restrict__ pe,
                                          int nblk, uint32 cb,
                                          float& a0, float& a1) {
    uint2 ma[8], mb[8];
    uint32 u[8];
    PREFETCH8(ma, 0)
    int b = 0;
    for (; b + 2 <= nblk; b += 2) {
        GATHER8(ma)
        PREFETCH8(mb, b + 1)
        FMA8(ma)
        GATHER8(mb)
        PREFETCH8(ma, b + 2)
        FMA8(mb)
    }
    if (b < nblk) {
        GATHER8(ma)
        FMA8(ma)
    }
}

// ---------- chunked SpMM, hop 1 (both supports fused, src = m0, beta = 0) ----------
// bx&7 XCD swizzle + per-XCD chunk set (R1 config: best measured, 312us).
__global__ __launch_bounds__(256) void k_spmm1(const u16* __restrict__ src,
                                               u16* __restrict__ dst0,
                                               u16* __restrict__ dst1,
                                               const int* __restrict__ rowptr,
                                               const uint2* __restrict__ pedges) {
    const int bx = blockIdx.x;
    const int xcd = bx & (NXCD - 1);
    const int l = bx >> 3;                       // 0 .. 4*5000-1 per XCD
    const int cwx = l / (2 * (NN / 4));          // chunk-within-xcd, 0..3
    const int r2 = l - cwx * (2 * (NN / 4));
    const int chunk = xcd * (NCHUNK / NXCD) + cwx;
    const int s = r2 & 1;
    const int quad = r2 >> 1;
    const int wave = threadIdx.x >> 6, lane = threadIdx.x & 63;
    const int row = quad * 4 + wave;
    const uint32 cb = (uint32)chunk * CHUNK_B + (uint32)lane * 4;  // byte offset in row
    const int* rp = rowptr + s * RPS;
    const int e0 = __builtin_amdgcn_readfirstlane(rp[row]);
    const int e1 = __builtin_amdgcn_readfirstlane(rp[row + 1]);
    const uint2* pe = pedges + (size_t)s * PEPAD + e0;
    float a0 = 0.f, a1 = 0.f;
    spmm_core((const char*)src, pe, (e1 - e0) >> 3, cb, a0, a1);
    u16* dst = s ? dst1 : dst0;
    uint32 o = (uint32)f2bf(a0) | ((uint32)f2bf(a1) << 16);
    __builtin_nontemporal_store(o, (uint32*)((char*)dst + (size_t)row * (CB * 2) + cb));
}

// ---------- merged chunked SpMM, hop 2 (both supports): dst = 2*A*src - m0 ----------
// single launch (saves a bubble); support-inner within each chunk slot
__global__ __launch_bounds__(256) void k_spmm2(const u16* __restrict__ src0,
                                               const u16* __restrict__ src1,
                                               const u16* __restrict__ aux,
                                               u16* __restrict__ dst0,
                                               u16* __restrict__ dst1,
                                               const int* __restrict__ rowptr,
                                               const uint2* __restrict__ pedges) {
    const int bx = blockIdx.x;
    const int xcd = bx & (NXCD - 1);
    const int l = bx >> 3;
    const int cwx = l / (2 * (NN / 4));
    const int r2 = l - cwx * (2 * (NN / 4));
    const int chunk = xcd * (NCHUNK / NXCD) + cwx;
    const int s = r2 / (NN / 4);
    const int quad = r2 - s * (NN / 4);
    const int wave = threadIdx.x >> 6, lane = threadIdx.x & 63;
    const int row = quad * 4 + wave;
    const uint32 cb = (uint32)chunk * CHUNK_B + (uint32)lane * 4;
    const int* rp = rowptr + s * RPS;
    const int e0 = __builtin_amdgcn_readfirstlane(rp[row]);
    const int e1 = __builtin_amdgcn_readfirstlane(rp[row + 1]);
    const uint2* pe = pedges + (size_t)s * PEPAD + e0;
    const char* srcb = (const char*)(s ? src1 : src0);
    float a0 = 0.f, a1 = 0.f;
    spmm_core(srcb, pe, (e1 - e0) >> 3, cb, a0, a1);
    const size_t rowoff = (size_t)row * (CB * 2) + cb;
    uint32 av = __builtin_nontemporal_load((const uint32*)((const char*)aux + rowoff));
    float c0 = 2.f * a0 - __uint_as_float(av << 16);
    float c1 = 2.f * a1 - __uint_as_float(av & 0xffff0000u);
    uint32 o = (uint32)f2bf(c0) | ((uint32)f2bf(c1) << 16);
    u16* dst = s ? dst1 : dst0;
    __builtin_nontemporal_store(o, (uint32*)((char*)dst + rowoff));
}

// ---------- phase 2: per-node (64 x 320) @ (320 x 64) via MFMA, bias fused ----------
__global__ __launch_bounds__(256) void k_gemm(const u16* __restrict__ mats,
                                              const u16* __restrict__ thetaFrag,
                                              const float* __restrict__ bias,
                                              float* __restrict__ out) {
    __shared__ u16 th[20480];   // 40KB
    const int tid = threadIdx.x;
    #pragma unroll
    for (int q = 0; q < 10; ++q) {
        int idx = tid * 8 + q * 2048;
        *(u16x8*)&th[idx] = *(const u16x8*)&thetaFrag[idx];
    }
    __syncthreads();
    const int wave = tid >> 6, lane = tid & 63;
    const int node = blockIdx.x * 4 + wave;
    const int l15 = lane & 15, lhi = lane >> 4;

    f32x4 acc[4][4];
    #pragma unroll
    for (int ct = 0; ct < 4; ++ct) {
        float bv = bias[ct * 16 + l15];
        #pragma unroll
        for (int bt = 0; bt < 4; ++bt) {
            acc[bt][ct][0] = bv; acc[bt][ct][1] = bv; acc[bt][ct][2] = bv; acc[bt][ct][3] = bv;
        }
    }
    #pragma unroll
    for (int ks = 0; ks < 10; ++ks) {
        const int m = ks >> 1;
        const int c0 = ((ks & 1) << 5) + (lhi << 3);
        const u16* mbase = mats + (size_t)m * ((size_t)NN * CB) + (size_t)node * CB;
        bf16x8 af[4];
        #pragma unroll
        for (int bt = 0; bt < 4; ++bt)
            af[bt] = *(const bf16x8*)(mbase + (bt * 16 + l15) * 64 + c0);
        #pragma unroll
        for (int ct = 0; ct < 4; ++ct) {
            bf16x8 bf = *(const bf16x8*)&th[((ks * 4 + ct) * 64 + lane) * 8];
            #pragma unroll
            for (int bt = 0; bt < 4; ++bt)
                acc[bt][ct] = __builtin_amdgcn_mfma_f32_16x16x32_bf16(af[bt], bf, acc[bt][ct], 0, 0, 0);
        }
    }
    #pragma unroll
    for (int bt = 0; bt < 4; ++bt)
        #pragma unroll
        for (int ct = 0; ct < 4; ++ct)
            #pragma unroll
            for (int r = 0; r < 4; ++r) {
                int b = bt * 16 + lhi * 4 + r;
                int co = ct * 16 + l15;
                __builtin_nontemporal_store(acc[bt][ct][r],
                    &out[(size_t)b * (NN * 64) + (size_t)node * 64 + co]);
            }
}

extern "C" void kernel_launch(void* const* d_in, const int* in_sizes, int n_in,
                              void* d_out, int out_size, void* d_ws, size_t ws_size,
                              hipStream_t stream) {
    const float* x         = (const float*)d_in[0];
    const float* edge_vals = (const float*)d_in[1];
    const float* Theta     = (const float*)d_in[2];
    const float* bias      = (const float*)d_in[3];
    const int*   edge_rows = (const int*)d_in[4];
    const int*   edge_cols = (const int*)d_in[5];
    float* out = (float*)d_out;

    uint8_t* ws = (uint8_t*)d_ws;
    const size_t MAT_E = (size_t)NN * CB;      // 40,960,000 elements
    const size_t MAT_B = MAT_E * 2;            // bytes per bf16 matrix

    u16* mats      = (u16*)ws;                          // 5 contiguous matrices
    u16* thetaFrag = (u16*)(ws + 5 * MAT_B);
    uint8_t* p = ws + 5 * MAT_B + 40960;
    int* counts = (int*)p;  p += (size_t)NSUP * RPS * 4;
    int* rowptr = (int*)p;  p += (size_t)NSUP * RPS * 4;
    int* cursor = (int*)p;  p += (size_t)NSUP * RPS * 4;
    p = (uint8_t*)(((uintptr_t)p + 255) & ~(uintptr_t)255);
    uint2* pedges = (uint2*)p;                          // 2 * PEPAD * 8B (zero-padded CSR)

    u16* m0 = mats;
    u16* m1 = mats + MAT_E;
    u16* m2 = mats + 2 * MAT_E;
    u16* m3 = mats + 3 * MAT_E;
    u16* m4 = mats + 4 * MAT_E;

    // phase 0 + CSR build + Theta pack
    k_transpose<<<NN, 256, 0, stream>>>(x, m0);
    k_zero<<<(NSUP * RPS + 255) / 256, 256, 0, stream>>>(counts, NSUP * RPS);
    k_zero<<<(NSUP * PEPAD * 2 + 255) / 256, 256, 0, stream>>>((int*)pedges, NSUP * PEPAD * 2);
    k_hist<<<(NSUP * NE) / 256, 256, 0, stream>>>(edge_rows, counts);
    k_scan<<<NSUP, 1024, 0, stream>>>(counts, rowptr, cursor);
    k_scatter<<<(NSUP * NE) / 256, 256, 0, stream>>>(edge_rows, edge_cols, edge_vals,
                                                     cursor, pedges);
    k_theta<<<80, 256, 0, stream>>>(Theta, thetaFrag);

    // diffusion chain, column-chunked for L2 residency; chunks pinned per-XCD
    k_spmm1<<<NCHUNK * (NN / 4) * 2, 256, 0, stream>>>(m0, m1, m3, rowptr, pedges);
    k_spmm2<<<NCHUNK * (NN / 4) * 2, 256, 0, stream>>>(m1, m3, m0, m2, m4,
                                                       rowptr, pedges);

    // output projection
    k_gemm<<<NN / 4, 256, 0, stream>>>(mats, thetaFrag, bias, out);
}